// Round 14
// baseline (376.824 us; speedup 1.0000x reference)
//
#include <hip/hip_runtime.h>
#include <cstdint>
#include <cstddef>

typedef unsigned short u16;
typedef unsigned int u32;
typedef __attribute__((ext_vector_type(4))) u16 u16x4;
typedef __attribute__((ext_vector_type(8))) u16 u16x8;
typedef __attribute__((ext_vector_type(4))) float f32x4;
typedef __attribute__((ext_vector_type(8))) __bf16 bf16x8;

#define DEV static __device__ __forceinline__

DEV u16 f2bf(float f) {  // HW RTNE convert
  __bf16 h = (__bf16)f;
  return __builtin_bit_cast(u16, h);
}
DEV float bf2f(u16 s) { return __builtin_bit_cast(float, (u32)s << 16); }
DEV float sigm(float x) { return __builtin_amdgcn_rcpf(1.f + __expf(-x)); }

DEV void gl_lds16(const void* g, void* l) {
  __builtin_amdgcn_global_load_lds((const __attribute__((address_space(1))) u32*)g,
                                   (__attribute__((address_space(3))) u32*)l, 16, 0, 0);
}

constexpr int B_ = 2, L_ = 4096, H_ = 8;
constexpr int BL = B_ * L_;   // 8192 tokens
constexpr int NC = L_ / 32;   // 128 chunks per sequence
constexpr int QKV_N = 3200;   // 3*1024 qkv + 16 beta/mix logit cols + 112 pad

// blob layout per (bh,chunk), u16 element offsets; total 17408 elems = 34816 B
constexpr int WOFF = 0;       // w   A-frags: ((mw*4+ks)*64 + lane)*8 + e
constexpr int QOFF = 4096;    // q   A-frags: same mapping
constexpr int KTOFF = 8192;   // k^T A-frags: (mi*64 + lane)*8 + e
constexpr int AOFF = 12288;   // attn A-frags: (mw*64 + lane)*8 + e
constexpr int UTOFF = 13312;  // u^T  frags: ((sg*2+mw)*64 + lane)*4 + r
constexpr int BLOB_ELEMS = 17408;

// ---------------------------------------------------------------------------
__global__ __launch_bounds__(256) void k_f32_to_bf16(const float* __restrict__ src,
                                                     u16* __restrict__ dst, int n4) {
  int i = blockIdx.x * 256 + threadIdx.x;
  if (i < n4) {
    f32x4 v = *(const f32x4*)(src + (size_t)i * 4);
    u16x4 o;
#pragma unroll
    for (int j = 0; j < 4; ++j) o[j] = f2bf(v[j]);
    *(u16x4*)(dst + (size_t)i * 4) = o;
  }
}

// ---------------------------------------------------------------------------
// transpose 1024x1024 f32 weights -> bf16 [n][k]; q,k,v go into one [3200][1024]
// ---------------------------------------------------------------------------
__global__ __launch_bounds__(256) void k_transpose_w(const float* __restrict__ s0, const float* __restrict__ s1,
                                                     const float* __restrict__ s2, const float* __restrict__ s3,
                                                     u16* __restrict__ d0, u16* __restrict__ d1,
                                                     u16* __restrict__ d2, u16* __restrict__ d3) {
  const float* src = blockIdx.z == 0 ? s0 : blockIdx.z == 1 ? s1 : blockIdx.z == 2 ? s2 : s3;
  u16* dst = blockIdx.z == 0 ? d0 : blockIdx.z == 1 ? d1 : blockIdx.z == 2 ? d2 : d3;
  __shared__ float tile[32][33];
  int k0 = blockIdx.y * 32, n0 = blockIdx.x * 32;
  int ty = threadIdx.x >> 5, tx = threadIdx.x & 31;
#pragma unroll
  for (int i = 0; i < 4; ++i)
    tile[ty + 8 * i][tx] = src[(size_t)(k0 + ty + 8 * i) * 1024 + n0 + tx];
  __syncthreads();
#pragma unroll
  for (int i = 0; i < 4; ++i) {
    int nl = ty + 8 * i;
    dst[(size_t)(n0 + nl) * 1024 + k0 + tx] = f2bf(tile[tx][nl]);
  }
}

// pack b_w (1024x8) and mix_w (1024x8) transposed into wqkvT rows 3072..3087
__global__ __launch_bounds__(256) void k_pack_bg(const float* __restrict__ b_w, const float* __restrict__ mix_w,
                                                 u16* __restrict__ dst) {
  int idx = blockIdx.x * 256 + threadIdx.x;  // 0..16383
  int r = idx >> 10, d = idx & 1023;
  float v = r < 8 ? b_w[d * 8 + r] : mix_w[d * 8 + (r - 8)];
  dst[(size_t)r * 1024 + d] = f2bf(v);
}

// ---------------------------------------------------------------------------
// bf16 GEMM: C[M,N] = A[M,K] * Bt[N,K]^T ; 128x128 tile, 4 waves, 16x16x32 MFMA
// XCD-chunked block swizzle (requires grid count % 8 == 0).
// A-operand: direct global->register fragments, double-buffered (halves LDS
// traffic -- the measured bottleneck at R13: 1030cy LDS vs 310cy MFMA).
// B-operand: LDS-staged via global_load_lds, BK=64, 2 buffers, 8-slot XOR
// swizzle (store gk = kt+((pslot^row&7)<<3); read slot (kk*4+g)^l7 -> linear).
// ---------------------------------------------------------------------------
template<bool STORE_BF16>
__global__ __launch_bounds__(256, 2) void gemm_bt(const u16* __restrict__ A, const u16* __restrict__ Bt,
                                                  void* __restrict__ Cout, int M, int N, int K) {
  __shared__ u16 Bsh[2][128 * 64];
  const int tid = threadIdx.x;
  const int lane = tid & 63, w = tid >> 6;
  const int wr = w >> 1, wc = w & 1;
  const int g = lane >> 4, li = lane & 15;
  const int l7 = li & 7;
  const int nbx = gridDim.x * gridDim.y;
  const int bid = blockIdx.y * gridDim.x + blockIdx.x;
  const int wg = (bid & 7) * (nbx >> 3) + (bid >> 3);
  const int mblk = (wg / gridDim.x) * 128, nblk = (wg % gridDim.x) * 128;

  auto stageB = [&](int bsel, int t) {
    int kt = t << 6;
#pragma unroll
    for (int i = 0; i < 4; ++i) {
      int unit = i * 256 + tid;          // 0..1023 : 16B units of a 128x64 tile
      int row = unit >> 3, pslot = unit & 7;
      int gk = kt + ((pslot ^ (row & 7)) << 3);
      gl_lds16(Bt + (size_t)(nblk + row) * K + gk, (char*)Bsh[bsel] + unit * 16);
    }
  };
  const u16* abase = A + (size_t)(mblk + wr * 64 + li) * K + g * 8;
  auto loadA = [&](bf16x8 (&af)[8], int t) {
    int kt = t << 6;
#pragma unroll
    for (int kk = 0; kk < 2; ++kk)
#pragma unroll
      for (int m = 0; m < 4; ++m)
        af[kk * 4 + m] = *(const bf16x8*)(abase + (size_t)(m * 16) * K + kt + kk * 32);
  };

  f32x4 acc[4][4];
#pragma unroll
  for (int m = 0; m < 4; ++m)
#pragma unroll
    for (int n = 0; n < 4; ++n) acc[m][n] = (f32x4){0.f, 0.f, 0.f, 0.f};

  auto computeK = [&](const bf16x8 (&af)[8], const u16* bsh) {
#pragma unroll
    for (int kk = 0; kk < 2; ++kk) {
      const int slot = ((kk * 4 + g) ^ l7) << 3;
      bf16x8 bfr[4];
#pragma unroll
      for (int n = 0; n < 4; ++n) {
        int row = wc * 64 + n * 16 + li;
        bfr[n] = *(const bf16x8*)&bsh[row * 64 + slot];
      }
#pragma unroll
      for (int m = 0; m < 4; ++m)
#pragma unroll
        for (int n = 0; n < 4; ++n)
          acc[m][n] = __builtin_amdgcn_mfma_f32_16x16x32_bf16(af[kk * 4 + m], bfr[n], acc[m][n], 0, 0, 0);
    }
  };

  const int nsteps = K >> 6;           // K % 128 == 0 (1024): nsteps even
  bf16x8 afA[8], afB[8];
  stageB(0, 0);
  loadA(afA, 0);
  __syncthreads();                     // drain prologue stage

  for (int t = 0; t < nsteps; t += 2) {
    if (t + 1 < nsteps) { stageB(1, t + 1); loadA(afB, t + 1); }
    computeK(afA, Bsh[0]);
    __syncthreads();                   // Bsh[1] staged; reads of Bsh[0] done
    if (t + 2 < nsteps) { stageB(0, t + 2); loadA(afA, t + 2); }
    if (t + 1 < nsteps) computeK(afB, Bsh[1]);
    __syncthreads();                   // Bsh[0] staged; reads of Bsh[1] done
  }

#pragma unroll
  for (int m = 0; m < 4; ++m)
#pragma unroll
    for (int n = 0; n < 4; ++n)
#pragma unroll
      for (int r = 0; r < 4; ++r) {
        int grow = mblk + wr * 64 + m * 16 + g * 4 + r;
        int gcol = nblk + wc * 64 + n * 16 + li;
        if constexpr (STORE_BF16)
          ((u16*)Cout)[(size_t)grow * N + gcol] = f2bf(acc[m][n][r]);
        else
          ((float*)Cout)[(size_t)grow * N + gcol] = acc[m][n][r];
      }
}

// ---------------------------------------------------------------------------
// causal depthwise conv(K=4) + SiLU + per-head l2norm(q,k) + beta scaling.
// Token-tiled: block = (bh, 32-token tile); q/k/v head-slices staged in LDS.
// ---------------------------------------------------------------------------
__global__ __launch_bounds__(256) void k_conv(const u16* __restrict__ qkv,
                                              const float* __restrict__ cqw, const float* __restrict__ ckw,
                                              const float* __restrict__ cvw,
                                              const float* __restrict__ mix_b, const float* __restrict__ mix_bias,
                                              u16* __restrict__ qn, u16* __restrict__ kn, u16* __restrict__ kb,
                                              u16* __restrict__ vb, u16* __restrict__ vtok,
                                              float* __restrict__ gg) {
  const int blk = blockIdx.x;          // bh*128 + tile
  const int bh = blk >> 7, tile = blk & 127;
  const int b = bh >> 3, h = bh & 7;
  const int t0 = tile * 32;
  const int tid = threadIdx.x;
  __shared__ u16 lq[35 * 136], lk[35 * 136], lv[35 * 136];
  __shared__ float bval[32];

  // ---- stage 35 token-rows x 128 ch x 3 streams into LDS (zero left pad) ----
#pragma unroll
  for (int it = 0; it < 7; ++it) {
    int li = it * 256 + tid;
    if (li >= 1680) break;              // 3 streams * 35 rows * 16 chunks
    int strm = li / 560;
    int rem = li - strm * 560;
    int row = rem >> 4, e8 = rem & 15;
    int l = t0 - 3 + row;
    u16* dst = strm == 0 ? lq : strm == 1 ? lk : lv;
    u16x8 val = (u16x8){0, 0, 0, 0, 0, 0, 0, 0};
    if (l >= 0)
      val = *(const u16x8*)(qkv + (size_t)(b * L_ + l) * QKV_N + strm * 1024 + h * 128 + e8 * 8);
    *(u16x8*)&dst[row * 136 + e8 * 8] = val;
  }
  if (tid < 32) {  // beta + g logits for this tile's 32 tokens
    int gt = b * L_ + t0 + tid;
    bval[tid] = sigm(bf2f(qkv[(size_t)gt * QKV_N + 3072 + h]));
    float gz = bf2f(qkv[(size_t)gt * QKV_N + 3080 + h]) + mix_b[h] + mix_bias[h];
    gg[gt * 8 + h] = sigm(gz);
  }
  __syncthreads();

  // ---- each thread: one token x 16 channels ----
  const int tok = tid >> 3, cg = tid & 7;
  const int l = t0 + tok;
  float aq[16], ak[16], av[16];

  auto do_stream = [&](const u16* lbuf, const float* wbase, float* acc) {
    u16x8 r0[4], r1[4];
#pragma unroll
    for (int i = 0; i < 4; ++i) {
      int base = (tok + i) * 136 + cg * 16;
      r0[i] = *(const u16x8*)&lbuf[base];
      r1[i] = *(const u16x8*)&lbuf[base + 8];
    }
#pragma unroll
    for (int e = 0; e < 8; ++e) {
      f32x4 w0 = *(const f32x4*)(wbase + e * 4);
      f32x4 w1 = *(const f32x4*)(wbase + (e + 8) * 4);
      float s0 = 0.f, s1 = 0.f;
#pragma unroll
      for (int i = 0; i < 4; ++i) {
        s0 += bf2f(r0[i][e]) * w0[i];
        s1 += bf2f(r1[i][e]) * w1[i];
      }
      acc[e] = s0;
      acc[e + 8] = s1;
    }
  };
  const int chb = (h * 128 + cg * 16) * 4;
  do_stream(lq, cqw + chb, aq);
  do_stream(lk, ckw + chb, ak);
  do_stream(lv, cvw + chb, av);

  float sq2 = 0.f, sk2 = 0.f;
#pragma unroll
  for (int e = 0; e < 16; ++e) {
    aq[e] = aq[e] * sigm(aq[e]);
    ak[e] = ak[e] * sigm(ak[e]);
    av[e] = av[e] * sigm(av[e]);
    sq2 += aq[e] * aq[e];
    sk2 += ak[e] * ak[e];
  }
#pragma unroll
  for (int m = 1; m <= 4; m <<= 1) {
    sq2 += __shfl_xor(sq2, m);
    sk2 += __shfl_xor(sk2, m);
  }
  float rq = rsqrtf(sq2 + 1e-12f), rk = rsqrtf(sk2 + 1e-12f);
  float bv = bval[tok];
  size_t hoff = ((size_t)bh * L_ + l) * 128 + cg * 16;
  size_t toff = ((size_t)(b * L_ + l)) * 1024 + h * 128 + cg * 16;
#pragma unroll
  for (int part = 0; part < 2; ++part) {
    u16x8 oq, ok, okb, ovb, ovt;
#pragma unroll
    for (int e = 0; e < 8; ++e) {
      float q = aq[part * 8 + e] * rq;
      float kk = ak[part * 8 + e] * rk;
      float vv = av[part * 8 + e];
      oq[e] = f2bf(q);
      ok[e] = f2bf(kk);
      okb[e] = f2bf(kk * bv);
      ovb[e] = f2bf(vv * bv);
      ovt[e] = f2bf(vv);
    }
    *(u16x8*)(qn + hoff + part * 8) = oq;
    *(u16x8*)(kn + hoff + part * 8) = ok;
    *(u16x8*)(kb + hoff + part * 8) = okb;
    *(u16x8*)(vb + hoff + part * 8) = ovb;
    *(u16x8*)(vtok + toff + part * 8) = ovt;
  }
}

// ---------------------------------------------------------------------------
// per-(bh,chunk): X = (I + strict_tril(kb@kn^T))^-1 ; u=X@vb ; w=X@kb ;
// attn = tril(qn@kn^T). MFMA for all matrix products; wave-specialized phases.
// Outputs packed in MFMA-fragment blob for the scan.
// ---------------------------------------------------------------------------
__global__ __launch_bounds__(256) void k_chunkprep(const u16* __restrict__ qn, const u16* __restrict__ kn,
                                                   const u16* __restrict__ kb, const u16* __restrict__ vb,
                                                   u16* __restrict__ blob) {
  const int blk = blockIdx.x;  // bh*NC + chunk
  const int bh = blk >> 7, ch = blk & 127;
  const int tid = threadIdx.x;
  const int wave = tid >> 6, lane = tid & 63;
  const int g = lane >> 4, li = lane & 15;
  __shared__ u16 kbl[32 * 136], knl[32 * 136], vbl[32 * 136], qnl[32 * 136];
  __shared__ float Af[32][33];   // kb@kn^T (f32)
  __shared__ float Qs[32][33];   // tril(qn@kn^T) (f32)
  __shared__ float Xs[32][33];   // inverse (f32)
  __shared__ float Ts[16][17];   // A21@X11 temp
  __shared__ u16 w_s[32 * 136];  // w row-major bf16

  size_t base = ((size_t)bh * L_ + (size_t)ch * 32) * 128;
#pragma unroll
  for (int rep = 0; rep < 2; ++rep) {
    int lin = rep * 2048 + tid * 8;
    int row = lin >> 7, col = lin & 127;
    *(u16x8*)&kbl[row * 136 + col] = *(const u16x8*)(kb + base + lin);
    *(u16x8*)&knl[row * 136 + col] = *(const u16x8*)(kn + base + lin);
    *(u16x8*)&vbl[row * 136 + col] = *(const u16x8*)(vb + base + lin);
    *(u16x8*)&qnl[row * 136 + col] = *(const u16x8*)(qn + base + lin);
  }
  __syncthreads();

  u16* bp = blob + (size_t)blk * BLOB_ELEMS;

  // ---- phase 1: MFMA products + kt transpose ----
  if (wave < 2) {
    const u16* asrc = (wave == 0) ? kbl : qnl;
    bf16x8 a[2][4], bfr[2][4];
#pragma unroll
    for (int mt = 0; mt < 2; ++mt)
#pragma unroll
      for (int ks = 0; ks < 4; ++ks) {
        a[mt][ks] = *(const bf16x8*)&asrc[(mt * 16 + li) * 136 + ks * 32 + g * 8];
        bfr[mt][ks] = *(const bf16x8*)&knl[(mt * 16 + li) * 136 + ks * 32 + g * 8];
      }
    f32x4 acc[2][2];
#pragma unroll
    for (int mt = 0; mt < 2; ++mt)
#pragma unroll
      for (int nt = 0; nt < 2; ++nt) acc[mt][nt] = (f32x4){0.f, 0.f, 0.f, 0.f};
#pragma unroll
    for (int mt = 0; mt < 2; ++mt)
#pragma unroll
      for (int nt = 0; nt < 2; ++nt)
#pragma unroll
        for (int ks = 0; ks < 4; ++ks)
          acc[mt][nt] = __builtin_amdgcn_mfma_f32_16x16x32_bf16(a[mt][ks], bfr[nt][ks], acc[mt][nt], 0, 0, 0);
    if (wave == 0) {
#pragma unroll
      for (int mt = 0; mt < 2; ++mt)
#pragma unroll
        for (int nt = 0; nt < 2; ++nt)
#pragma unroll
          for (int r = 0; r < 4; ++r)
            Af[mt * 16 + g * 4 + r][nt * 16 + li] = acc[mt][nt][r];
    } else {
#pragma unroll
      for (int mt = 0; mt < 2; ++mt)
#pragma unroll
        for (int nt = 0; nt < 2; ++nt)
#pragma unroll
          for (int r = 0; r < 4; ++r) {
            int row = mt * 16 + g * 4 + r, col = nt * 16 + li;
            Qs[row][col] = (col <= row) ? acc[mt][nt][r] : 0.f;
          }
    }
  } else {
    // kt A-frags: kt[dk][c] = kn[c][dk]; v8 units 0..511 over waves 2,3
#pragma unroll
    for (int it = 0; it < 4; ++it) {
      int v8 = (tid - 128) * 4 + it;
      int f = v8 >> 6, l = v8 & 63;
      int lli = l & 15, lg = l >> 4;
      int dk = f * 16 + lli;
      u16x8 tv;
#pragma unroll
      for (int e = 0; e < 8; ++e) tv[e] = knl[(lg * 8 + e) * 136 + dk];
      *(u16x8*)(bp + KTOFF + (size_t)v8 * 8) = tv;
    }
  }
  __syncthreads();

  // ---- phase 2: solve (wave 0) || AOFF pack (wave 1) ----
  if (wave == 0) {
    if (lane < 32) {
      for (int i = 0; i < 32; ++i) Xs[i][lane] = (i == lane) ? 1.f : 0.f;
      int hb = lane >> 4, j = lane & 15, b0 = hb * 16;
      // column-parallel 16x16 unit-lower-triangular inverse (X11, X22)
      for (int i = j + 1; i < 16; ++i) {
        float s = 0.f;
        for (int m = j; m < i; ++m) s += Af[b0 + i][b0 + m] * Xs[b0 + m][b0 + j];
        Xs[b0 + i][b0 + j] = -s;
      }
    }
    asm volatile("s_waitcnt lgkmcnt(0)" ::: "memory");
    // T = A21 @ X11  (A21 = Af[16:32][0:16])
#pragma unroll
    for (int t = 0; t < 4; ++t) {
      int idx = lane * 4 + t;
      int i = idx >> 4, j = idx & 15;
      float s = 0.f;
      for (int m = 0; m < 16; ++m) s += Af[16 + i][m] * Xs[m][j];
      Ts[i][j] = s;
    }
    asm volatile("s_waitcnt lgkmcnt(0)" ::: "memory");
    // X21 = -X22 @ T
#pragma unroll
    for (int t = 0; t < 4; ++t) {
      int idx = lane * 4 + t;
      int i = idx >> 4, j = idx & 15;
      float s = 0.f;
      for (int m = 0; m < 16; ++m) s += Xs[16 + i][16 + m] * Ts[m][j];
      Xs[16 + i][j] = -s;
    }
  } else if (wave == 1) {
    // AOFF pack: attn A-frags from Qs
#pragma unroll
    for (int mw = 0; mw < 2; ++mw) {
      u16x8 tv;
#pragma unroll
      for (int e = 0; e < 8; ++e) tv[e] = f2bf(Qs[mw * 16 + li][g * 8 + e]);
      *(u16x8*)(bp + AOFF + (size_t)(mw * 64 + lane) * 8) = tv;
    }
  }
  __syncthreads();

  // ---- phase 3: u = X@vb (waves 0,1 -> UTOFF direct) ; w = X@kb (waves 2,3 -> w_s) ----
  {
    bf16x8 xa[2];
#pragma unroll
    for (int mw = 0; mw < 2; ++mw) {
      u16x8 xv;
#pragma unroll
      for (int e = 0; e < 8; ++e) xv[e] = f2bf(Xs[mw * 16 + li][g * 8 + e]);
      xa[mw] = __builtin_bit_cast(bf16x8, xv);
    }
    const u16* bsrc = (wave < 2) ? vbl : kbl;
    const int wsel = wave & 1;
#pragma unroll
    for (int s4 = 0; s4 < 4; ++s4) {
      int sg = wsel * 4 + s4;
      u16x8 bv;
#pragma unroll
      for (int e = 0; e < 8; ++e) bv[e] = bsrc[(g * 8 + e) * 136 + sg * 16 + li];
      bf16x8 bfrag = __builtin_bit_cast(bf16x8, bv);
      f32x4 a0 = (f32x4){0.f, 0.f, 0.f, 0.f};
      f32x4 a1 = (f32x4){0.f, 0.f, 0.f, 0.f};
      a0 = __builtin_amdgcn_mfma_f32_16x16x32_bf16(xa[0], bfrag, a0, 0, 0, 0);
      a1 = __builtin_amdgcn_mfma_f32_16x16x32_bf16(xa[1], bfrag, a1, 0, 0, 0);
      if (wave < 2) {
        u16x4 o0, o1;
#pragma unroll
        for (int r = 0; r < 4; ++r) { o0[r] = f2bf(a0[r]); o1[r] = f2bf(a1[r]); }
        *(u16x4*)(bp + UTOFF + (size_t)((sg * 2 + 0) * 64 + lane) * 4) = o0;
        *(u16x4*)(bp + UTOFF + (size_t)((sg * 2 + 1) * 64 + lane) * 4) = o1;
      } else {
#pragma unroll
        for (int r = 0; r < 4; ++r) {
          w_s[(0 * 16 + g * 4 + r) * 136 + sg * 16 + li] = f2bf(a0[r]);
          w_s[(1 * 16 + g * 4 + r) * 136 + sg * 16 + li] = f2bf(a1[r]);
        }
      }
    }
  }
  __syncthreads();

  // ---- phase 4: WOFF (from w_s) + QOFF (from qnl) A-frag packs ----
#pragma unroll
  for (int it = 0; it < 2; ++it) {
    int v8 = tid * 2 + it;
    int f = v8 >> 6, l = v8 & 63;
    int lli = l & 15, lg = l >> 4;
    int mw = f >> 2, ks = f & 3;
    int row = mw * 16 + lli, c0 = ks * 32 + lg * 8;
    *(u16x8*)(bp + WOFF + (size_t)v8 * 8) = *(const u16x8*)&w_s[row * 136 + c0];
    *(u16x8*)(bp + QOFF + (size_t)v8 * 8) = *(const u16x8*)&qnl[row * 136 + c0];
  }
}

// ---------------------------------------------------------------------------
// sequential inter-chunk scan; 1 wave per block; block = (bh, dv-slice of 16).
// 2-deep register double-buffer (named sets, unrolled x2) hides L2 latency.
// Block swizzle groups all 8 dv-slices of a bh onto one XCD for L2 sharing.
// ---------------------------------------------------------------------------
struct Frags {
  bf16x8 aw[8], aq[8], akt[8], aat[2];
  u16x4 uv[2];
};

DEV void load_frags(Frags& f, const u16* __restrict__ bp, int lane, int sg) {
#pragma unroll
  for (int i = 0; i < 8; ++i)
    f.aw[i] = *(const bf16x8*)&bp[WOFF + ((size_t)(i * 64 + lane)) * 8];
#pragma unroll
  for (int mw = 0; mw < 2; ++mw)
    f.uv[mw] = *(const u16x4*)&bp[UTOFF + ((size_t)((sg * 2 + mw) * 64 + lane)) * 4];
#pragma unroll
  for (int i = 0; i < 8; ++i)
    f.aq[i] = *(const bf16x8*)&bp[QOFF + ((size_t)(i * 64 + lane)) * 8];
#pragma unroll
  for (int mw = 0; mw < 2; ++mw)
    f.aat[mw] = *(const bf16x8*)&bp[AOFF + ((size_t)(mw * 64 + lane)) * 8];
#pragma unroll
  for (int i = 0; i < 8; ++i)
    f.akt[i] = *(const bf16x8*)&bp[KTOFF + ((size_t)(i * 64 + lane)) * 8];
}

DEV void compute_chunk(const Frags& f, f32x4 (&S)[8], u16* st, u16* uft,
                       u16* __restrict__ o_out, size_t obase, int lane) {
  const int g = lane >> 4, li = lane & 15;
  // ---- export S (f32 acc, C-layout) -> bf16 transposed -> B-frags ----
#pragma unroll
  for (int mi = 0; mi < 8; ++mi) {
    u16x4 sv;
#pragma unroll
    for (int r = 0; r < 4; ++r) sv[r] = f2bf(S[mi][r]);
    *(u16x4*)&st[li * 136 + mi * 16 + g * 4] = sv;
  }
  bf16x8 bS[4];
#pragma unroll
  for (int ks = 0; ks < 4; ++ks)
    bS[ks] = *(const bf16x8*)&st[li * 136 + ks * 32 + g * 8];

  // t1 = w_i @ S  (split into two 2-deep chains to halve MFMA latency chain)
  f32x4 t1a[2], t1b[2];
#pragma unroll
  for (int mw = 0; mw < 2; ++mw) {
    t1a[mw] = (f32x4){0.f, 0.f, 0.f, 0.f};
    t1b[mw] = (f32x4){0.f, 0.f, 0.f, 0.f};
    t1a[mw] = __builtin_amdgcn_mfma_f32_16x16x32_bf16(f.aw[mw * 4 + 0], bS[0], t1a[mw], 0, 0, 0);
    t1b[mw] = __builtin_amdgcn_mfma_f32_16x16x32_bf16(f.aw[mw * 4 + 2], bS[2], t1b[mw], 0, 0, 0);
    t1a[mw] = __builtin_amdgcn_mfma_f32_16x16x32_bf16(f.aw[mw * 4 + 1], bS[1], t1a[mw], 0, 0, 0);
    t1b[mw] = __builtin_amdgcn_mfma_f32_16x16x32_bf16(f.aw[mw * 4 + 3], bS[3], t1b[mw], 0, 0, 0);
  }

  // ufix = u_i - t1 -> transposed LDS -> B-frag
#pragma unroll
  for (int mw = 0; mw < 2; ++mw) {
    u16x4 ufv;
#pragma unroll
    for (int r = 0; r < 4; ++r)
      ufv[r] = f2bf(bf2f(f.uv[mw][r]) - (t1a[mw][r] + t1b[mw][r]));
    *(u16x4*)&uft[li * 40 + mw * 16 + g * 4] = ufv;
  }
  bf16x8 bUF = *(const bf16x8*)&uft[li * 40 + g * 8];

  // o = q_i @ S + attn_i @ ufix
  f32x4 oa[2];
  oa[0] = (f32x4){0.f, 0.f, 0.f, 0.f};
  oa[1] = (f32x4){0.f, 0.f, 0.f, 0.f};
#pragma unroll
  for (int mw = 0; mw < 2; ++mw)
#pragma unroll
    for (int ks = 0; ks < 4; ++ks)
      oa[mw] = __builtin_amdgcn_mfma_f32_16x16x32_bf16(f.aq[mw * 4 + ks], bS[ks], oa[mw], 0, 0, 0);
#pragma unroll
  for (int mw = 0; mw < 2; ++mw)
    oa[mw] = __builtin_amdgcn_mfma_f32_16x16x32_bf16(f.aat[mw], bUF, oa[mw], 0, 0, 0);

  // write o (token-major)
#pragma unroll
  for (int mw = 0; mw < 2; ++mw)
#pragma unroll
    for (int r = 0; r < 4; ++r)
      o_out[obase + (size_t)(mw * 16 + r) * 1024] = f2bf(oa[mw][r]);

  // S += k_i^T @ ufix
#pragma unroll
  for (int mi = 0; mi < 8; ++mi)
    S[mi] = __builtin_amdgcn_mfma_f32_16x16x32_bf16(f.akt[mi], bUF, S[mi], 0, 0, 0);
}

__global__ __launch_bounds__(64, 1) void k_scan(const u16* __restrict__ blob, u16* __restrict__ o_out) {
  __shared__ u16 st[16 * 136];   // transposed S (bf16), padded stride 136
  __shared__ u16 uft[16 * 40];   // transposed ufix
  const int bid = blockIdx.x;    // 0..127
  const int bh = (bid & 7) | ((bid >> 6) << 3);
  const int sg = (bid >> 3) & 7;
  const int b = bh >> 3, h = bh & 7;
  const int lane = threadIdx.x;
  const int g = lane >> 4, li = lane & 15;

  f32x4 S[8];
#pragma unroll
  for (int mi = 0; mi < 8; ++mi) S[mi] = (f32x4){0.f, 0.f, 0.f, 0.f};

  const u16* gb = blob + (size_t)bh * NC * BLOB_ELEMS;
  const size_t ob0 = ((size_t)b * L_ + g * 4) * 1024 + h * 128 + sg * 16 + li;

  Frags fa, fb;
  load_frags(fa, gb, lane, sg);
  for (int ch = 0; ch < NC - 2; ch += 2) {
    load_frags(fb, gb + (size_t)(ch + 1) * BLOB_ELEMS, lane, sg);
    compute_chunk(fa, S, st, uft, o_out, ob0 + (size_t)ch * 32 * 1024, lane);
    load_frags(fa, gb + (size_t)(ch + 2) * BLOB_ELEMS, lane, sg);
    compute_chunk(fb, S, st, uft, o_out, ob0 + (size_t)(ch + 1) * 32 * 1024, lane);
  }
  load_frags(fb, gb + (size_t)(NC - 1) * BLOB_ELEMS, lane, sg);
  compute_chunk(fa, S, st, uft, o_out, ob0 + (size_t)(NC - 2) * 32 * 1024, lane);
  compute_chunk(fb, S, st, uft, o_out, ob0 + (size_t)(NC - 1) * 32 * 1024, lane);
}

// ---------------------------------------------------------------------------
// o = g*o + (1-g)*v_token ; RMS over DV ; * o_norm_w ; -> bf16 for final GEMM
// ---------------------------------------------------------------------------
__global__ __launch_bounds__(256) void k_mixnorm(const u16* __restrict__ o_mid, const u16* __restrict__ vtok,
                                                 const float* __restrict__ g, const float* __restrict__ onw,
                                                 u16* __restrict__ omix) {
  int t = blockIdx.x, tid = threadIdx.x;
  int c = tid * 4, h = c >> 7, dk = c & 127;
  float gv = g[t * 8 + h];
  u16x4 ov = *(const u16x4*)(o_mid + (size_t)t * 1024 + c);
  u16x4 vv = *(const u16x4*)(vtok + (size_t)t * 1024 + c);
  float mx[4];
#pragma unroll
  for (int j = 0; j < 4; ++j) mx[j] = gv * bf2f(ov[j]) + (1.f - gv) * bf2f(vv[j]);
  float ss = mx[0] * mx[0] + mx[1] * mx[1] + mx[2] * mx[2] + mx[3] * mx[3];
#pragma unroll
  for (int m = 1; m <= 16; m <<= 1) ss += __shfl_xor(ss, m);
  float r = rsqrtf(ss * (1.f / 128.f) + 1e-5f);
  u16x4 oo;
#pragma unroll
  for (int j = 0; j < 4; ++j) oo[j] = f2bf(mx[j] * r * onw[dk + j]);
  *(u16x4*)(omix + (size_t)t * 1024 + c) = oo;
}

// ---------------------------------------------------------------------------
extern "C" void kernel_launch(void* const* d_in, const int* in_sizes, int n_in,
                              void* d_out, int out_size, void* d_ws, size_t ws_size,
                              hipStream_t stream) {
  const float* hidden = (const float*)d_in[0];
  const float* q_w = (const float*)d_in[1];
  const float* k_w = (const float*)d_in[2];
  const float* v_w = (const float*)d_in[3];
  const float* cqw = (const float*)d_in[4];
  const float* ckw = (const float*)d_in[5];
  const float* cvw = (const float*)d_in[6];
  const float* b_w = (const float*)d_in[7];
  const float* mix_w = (const float*)d_in[8];
  const float* mix_b = (const float*)d_in[9];
  const float* mix_bias = (const float*)d_in[10];
  const float* onw = (const float*)d_in[11];
  const float* o_w = (const float*)d_in[12];

  char* ws = (char*)d_ws;
  size_t off = 0;
  auto alloc = [&](size_t bytes) {
    char* p = ws + off;
    off += (bytes + 255) & ~(size_t)255;
    return p;
  };
  u16* hbf = (u16*)alloc(16777216);      // hidden bf16; reused as omix at the end
  u16* wqkvT = (u16*)alloc((size_t)QKV_N * 1024 * 2);  // [3200][1024]
  u16* woT = (u16*)alloc(2097152);
  float* gg = (float*)alloc(262144);
  u16* qn = (u16*)alloc(16777216);       // reused as scan output o after chunkprep
  u16* kn = (u16*)alloc(16777216);
  u16* kbn = (u16*)alloc(16777216);
  u16* vbn = (u16*)alloc(16777216);
  u16* vtok = (u16*)alloc(16777216);
  u16* blob = (u16*)alloc(71303168);     // 16 bh * 128 ch * 34816 B (fragment blob)
  if (off > ws_size) return;

  // fused qkv GEMM output [8192][3200] aliases the (not-yet-written) blob
  // (safe: conv fully consumes qkv BEFORE chunkprep writes blob)
  u16* qkv = blob;
  u16* obuf = qn;  // scan output aliases qn (dead after chunkprep)

  k_f32_to_bf16<<<8192, 256, 0, stream>>>(hidden, hbf, 2097152);
  k_transpose_w<<<dim3(32, 32, 4), 256, 0, stream>>>(q_w, k_w, v_w, o_w,
                                                     wqkvT, wqkvT + 1024 * 1024,
                                                     wqkvT + 2 * 1024 * 1024, woT);
  k_pack_bg<<<64, 256, 0, stream>>>(b_w, mix_w, wqkvT + (size_t)3072 * 1024);
  gemm_bt<true><<<dim3(25, 64), 256, 0, stream>>>(hbf, wqkvT, qkv, BL, QKV_N, 1024);
  k_conv<<<2048, 256, 0, stream>>>(qkv, cqw, ckw, cvw, mix_b, mix_bias,
                                   qn, kn, kbn, vbn, vtok, gg);
  k_chunkprep<<<2048, 256, 0, stream>>>(qn, kn, kbn, vbn, blob);
  k_scan<<<128, 64, 0, stream>>>(blob, obuf);
  k_mixnorm<<<8192, 256, 0, stream>>>(obuf, vtok, gg, onw, hbf);
  gemm_bt<false><<<dim3(8, 64), 256, 0, stream>>>(hbf, woT, d_out, BL, 1024, 1024);
}

// Round 15
// 304.149 us; speedup vs baseline: 1.2389x; 1.2389x over previous
//
#include <hip/hip_runtime.h>
#include <cstdint>
#include <cstddef>

typedef unsigned short u16;
typedef unsigned int u32;
typedef __attribute__((ext_vector_type(4))) u16 u16x4;
typedef __attribute__((ext_vector_type(8))) u16 u16x8;
typedef __attribute__((ext_vector_type(4))) float f32x4;
typedef __attribute__((ext_vector_type(8))) __bf16 bf16x8;

#define DEV static __device__ __forceinline__

DEV u16 f2bf(float f) {  // HW RTNE convert
  __bf16 h = (__bf16)f;
  return __builtin_bit_cast(u16, h);
}
DEV float bf2f(u16 s) { return __builtin_bit_cast(float, (u32)s << 16); }
DEV float sigm(float x) { return __builtin_amdgcn_rcpf(1.f + __expf(-x)); }

DEV void gl_lds16(const void* g, void* l) {
  __builtin_amdgcn_global_load_lds((const __attribute__((address_space(1))) u32*)g,
                                   (__attribute__((address_space(3))) u32*)l, 16, 0, 0);
}

constexpr int B_ = 2, L_ = 4096, H_ = 8;
constexpr int BL = B_ * L_;   // 8192 tokens
constexpr int NC = L_ / 32;   // 128 chunks per sequence
constexpr int QKV_N = 3200;   // 3*1024 qkv + 16 beta/mix logit cols + 112 pad

// blob layout per (bh,chunk), u16 element offsets; total 17408 elems = 34816 B
constexpr int WOFF = 0;       // w   A-frags: ((mw*4+ks)*64 + lane)*8 + e
constexpr int QOFF = 4096;    // q   A-frags: same mapping
constexpr int KTOFF = 8192;   // k^T A-frags: (mi*64 + lane)*8 + e
constexpr int AOFF = 12288;   // attn A-frags: (mw*64 + lane)*8 + e
constexpr int UTOFF = 13312;  // u^T  frags: ((sg*2+mw)*64 + lane)*4 + r
constexpr int BLOB_ELEMS = 17408;

// ---------------------------------------------------------------------------
__global__ __launch_bounds__(256) void k_f32_to_bf16(const float* __restrict__ src,
                                                     u16* __restrict__ dst, int n4) {
  int i = blockIdx.x * 256 + threadIdx.x;
  if (i < n4) {
    f32x4 v = *(const f32x4*)(src + (size_t)i * 4);
    u16x4 o;
#pragma unroll
    for (int j = 0; j < 4; ++j) o[j] = f2bf(v[j]);
    *(u16x4*)(dst + (size_t)i * 4) = o;
  }
}

// ---------------------------------------------------------------------------
// transpose 1024x1024 f32 weights -> bf16 [n][k]; q,k,v go into one [3200][1024]
// ---------------------------------------------------------------------------
__global__ __launch_bounds__(256) void k_transpose_w(const float* __restrict__ s0, const float* __restrict__ s1,
                                                     const float* __restrict__ s2, const float* __restrict__ s3,
                                                     u16* __restrict__ d0, u16* __restrict__ d1,
                                                     u16* __restrict__ d2, u16* __restrict__ d3) {
  const float* src = blockIdx.z == 0 ? s0 : blockIdx.z == 1 ? s1 : blockIdx.z == 2 ? s2 : s3;
  u16* dst = blockIdx.z == 0 ? d0 : blockIdx.z == 1 ? d1 : blockIdx.z == 2 ? d2 : d3;
  __shared__ float tile[32][33];
  int k0 = blockIdx.y * 32, n0 = blockIdx.x * 32;
  int ty = threadIdx.x >> 5, tx = threadIdx.x & 31;
#pragma unroll
  for (int i = 0; i < 4; ++i)
    tile[ty + 8 * i][tx] = src[(size_t)(k0 + ty + 8 * i) * 1024 + n0 + tx];
  __syncthreads();
#pragma unroll
  for (int i = 0; i < 4; ++i) {
    int nl = ty + 8 * i;
    dst[(size_t)(n0 + nl) * 1024 + k0 + tx] = f2bf(tile[tx][nl]);
  }
}

// pack b_w (1024x8) and mix_w (1024x8) transposed into wqkvT rows 3072..3087
__global__ __launch_bounds__(256) void k_pack_bg(const float* __restrict__ b_w, const float* __restrict__ mix_w,
                                                 u16* __restrict__ dst) {
  int idx = blockIdx.x * 256 + threadIdx.x;  // 0..16383
  int r = idx >> 10, d = idx & 1023;
  float v = r < 8 ? b_w[d * 8 + r] : mix_w[d * 8 + (r - 8)];
  dst[(size_t)r * 1024 + d] = f2bf(v);
}

// ---------------------------------------------------------------------------
// bf16 GEMM: C[M,N] = A[M,K] * Bt[N,K]^T ; 128x128 tile, 4 waves, 16x16x32 MFMA
// XCD-chunked block swizzle (requires grid count % 8 == 0).
// BK=64 double-buffered LDS: STAGE(t+1) issued before compute(t); ONE barrier
// per 64-wide K-tile (halves barrier-drain stalls vs BK=32).
// 8-slot XOR swizzle (slot ^ row&7) keeps b128 reads bank-uniform (verified:
// SQ_LDS_BANK_CONFLICT == 0 at R13).
// ---------------------------------------------------------------------------
template<bool STORE_BF16>
__global__ __launch_bounds__(256) void gemm_bt(const u16* __restrict__ A, const u16* __restrict__ Bt,
                                               void* __restrict__ Cout, int M, int N, int K) {
  __shared__ u16 Ash[2][128 * 64];
  __shared__ u16 Bsh[2][128 * 64];
  const int tid = threadIdx.x;
  const int lane = tid & 63, w = tid >> 6;
  const int wr = w >> 1, wc = w & 1;
  const int g = lane >> 4, li = lane & 15;
  const int l7 = li & 7;
  const int nbx = gridDim.x * gridDim.y;
  const int bid = blockIdx.y * gridDim.x + blockIdx.x;
  const int wg = (bid & 7) * (nbx >> 3) + (bid >> 3);
  const int mblk = (wg / gridDim.x) * 128, nblk = (wg % gridDim.x) * 128;

  auto stage = [&](int bsel, int t) {
    int kt = t << 6;
#pragma unroll
    for (int i = 0; i < 4; ++i) {
      int unit = i * 256 + tid;          // 0..1023 : 16B units of a 128x64 tile
      int row = unit >> 3, pslot = unit & 7;
      int gslot = pslot ^ (row & 7);     // source col-group permutation
      int gk = kt + (gslot << 3);
      gl_lds16(A + (size_t)(mblk + row) * K + gk, (char*)Ash[bsel] + unit * 16);
      gl_lds16(Bt + (size_t)(nblk + row) * K + gk, (char*)Bsh[bsel] + unit * 16);
    }
  };

  f32x4 acc[4][4];
#pragma unroll
  for (int m = 0; m < 4; ++m)
#pragma unroll
    for (int n = 0; n < 4; ++n) acc[m][n] = (f32x4){0.f, 0.f, 0.f, 0.f};

  const int nsteps = K >> 6;
  stage(0, 0);
  __syncthreads();  // drain prologue stage

  for (int t = 0; t < nsteps; ++t) {
    const int cur = t & 1;
    if (t + 1 < nsteps) stage(cur ^ 1, t + 1);  // prefetch next K-tile

#pragma unroll
    for (int kk = 0; kk < 2; ++kk) {           // two 32-wide MFMA k-slices
      const int slot = ((kk * 4 + g) ^ l7) << 3;
      bf16x8 af[4], bfr[4];
#pragma unroll
      for (int m = 0; m < 4; ++m) {
        int row = wr * 64 + m * 16 + li;
        af[m] = *(const bf16x8*)&Ash[cur][row * 64 + slot];
      }
#pragma unroll
      for (int n = 0; n < 4; ++n) {
        int row = wc * 64 + n * 16 + li;
        bfr[n] = *(const bf16x8*)&Bsh[cur][row * 64 + slot];
      }
#pragma unroll
      for (int m = 0; m < 4; ++m)
#pragma unroll
        for (int n = 0; n < 4; ++n)
          acc[m][n] = __builtin_amdgcn_mfma_f32_16x16x32_bf16(af[m], bfr[n], acc[m][n], 0, 0, 0);
    }

    __syncthreads();  // reads of cur done + prefetch landed
  }

#pragma unroll
  for (int m = 0; m < 4; ++m)
#pragma unroll
    for (int n = 0; n < 4; ++n)
#pragma unroll
      for (int r = 0; r < 4; ++r) {
        int grow = mblk + wr * 64 + m * 16 + g * 4 + r;
        int gcol = nblk + wc * 64 + n * 16 + li;
        if constexpr (STORE_BF16)
          ((u16*)Cout)[(size_t)grow * N + gcol] = f2bf(acc[m][n][r]);
        else
          ((float*)Cout)[(size_t)grow * N + gcol] = acc[m][n][r];
      }
}

// ---------------------------------------------------------------------------
// causal depthwise conv(K=4) + SiLU + per-head l2norm(q,k) + beta scaling.
// Token-tiled: block = (bh, 32-token tile); q/k/v head-slices staged in LDS.
// ---------------------------------------------------------------------------
__global__ __launch_bounds__(256) void k_conv(const u16* __restrict__ qkv,
                                              const float* __restrict__ cqw, const float* __restrict__ ckw,
                                              const float* __restrict__ cvw,
                                              const float* __restrict__ mix_b, const float* __restrict__ mix_bias,
                                              u16* __restrict__ qn, u16* __restrict__ kn, u16* __restrict__ kb,
                                              u16* __restrict__ vb, u16* __restrict__ vtok,
                                              float* __restrict__ gg) {
  const int blk = blockIdx.x;          // bh*128 + tile
  const int bh = blk >> 7, tile = blk & 127;
  const int b = bh >> 3, h = bh & 7;
  const int t0 = tile * 32;
  const int tid = threadIdx.x;
  __shared__ u16 lq[35 * 136], lk[35 * 136], lv[35 * 136];
  __shared__ float bval[32];

  // ---- stage 35 token-rows x 128 ch x 3 streams into LDS (zero left pad) ----
#pragma unroll
  for (int it = 0; it < 7; ++it) {
    int li = it * 256 + tid;
    if (li >= 1680) break;              // 3 streams * 35 rows * 16 chunks
    int strm = li / 560;
    int rem = li - strm * 560;
    int row = rem >> 4, e8 = rem & 15;
    int l = t0 - 3 + row;
    u16* dst = strm == 0 ? lq : strm == 1 ? lk : lv;
    u16x8 val = (u16x8){0, 0, 0, 0, 0, 0, 0, 0};
    if (l >= 0)
      val = *(const u16x8*)(qkv + (size_t)(b * L_ + l) * QKV_N + strm * 1024 + h * 128 + e8 * 8);
    *(u16x8*)&dst[row * 136 + e8 * 8] = val;
  }
  if (tid < 32) {  // beta + g logits for this tile's 32 tokens
    int gt = b * L_ + t0 + tid;
    bval[tid] = sigm(bf2f(qkv[(size_t)gt * QKV_N + 3072 + h]));
    float gz = bf2f(qkv[(size_t)gt * QKV_N + 3080 + h]) + mix_b[h] + mix_bias[h];
    gg[gt * 8 + h] = sigm(gz);
  }
  __syncthreads();

  // ---- each thread: one token x 16 channels ----
  const int tok = tid >> 3, cg = tid & 7;
  const int l = t0 + tok;
  float aq[16], ak[16], av[16];

  auto do_stream = [&](const u16* lbuf, const float* wbase, float* acc) {
    u16x8 r0[4], r1[4];
#pragma unroll
    for (int i = 0; i < 4; ++i) {
      int base = (tok + i) * 136 + cg * 16;
      r0[i] = *(const u16x8*)&lbuf[base];
      r1[i] = *(const u16x8*)&lbuf[base + 8];
    }
#pragma unroll
    for (int e = 0; e < 8; ++e) {
      f32x4 w0 = *(const f32x4*)(wbase + e * 4);
      f32x4 w1 = *(const f32x4*)(wbase + (e + 8) * 4);
      float s0 = 0.f, s1 = 0.f;
#pragma unroll
      for (int i = 0; i < 4; ++i) {
        s0 += bf2f(r0[i][e]) * w0[i];
        s1 += bf2f(r1[i][e]) * w1[i];
      }
      acc[e] = s0;
      acc[e + 8] = s1;
    }
  };
  const int chb = (h * 128 + cg * 16) * 4;
  do_stream(lq, cqw + chb, aq);
  do_stream(lk, ckw + chb, ak);
  do_stream(lv, cvw + chb, av);

  float sq2 = 0.f, sk2 = 0.f;
#pragma unroll
  for (int e = 0; e < 16; ++e) {
    aq[e] = aq[e] * sigm(aq[e]);
    ak[e] = ak[e] * sigm(ak[e]);
    av[e] = av[e] * sigm(av[e]);
    sq2 += aq[e] * aq[e];
    sk2 += ak[e] * ak[e];
  }
#pragma unroll
  for (int m = 1; m <= 4; m <<= 1) {
    sq2 += __shfl_xor(sq2, m);
    sk2 += __shfl_xor(sk2, m);
  }
  float rq = rsqrtf(sq2 + 1e-12f), rk = rsqrtf(sk2 + 1e-12f);
  float bv = bval[tok];
  size_t hoff = ((size_t)bh * L_ + l) * 128 + cg * 16;
  size_t toff = ((size_t)(b * L_ + l)) * 1024 + h * 128 + cg * 16;
#pragma unroll
  for (int part = 0; part < 2; ++part) {
    u16x8 oq, ok, okb, ovb, ovt;
#pragma unroll
    for (int e = 0; e < 8; ++e) {
      float q = aq[part * 8 + e] * rq;
      float kk = ak[part * 8 + e] * rk;
      float vv = av[part * 8 + e];
      oq[e] = f2bf(q);
      ok[e] = f2bf(kk);
      okb[e] = f2bf(kk * bv);
      ovb[e] = f2bf(vv * bv);
      ovt[e] = f2bf(vv);
    }
    *(u16x8*)(qn + hoff + part * 8) = oq;
    *(u16x8*)(kn + hoff + part * 8) = ok;
    *(u16x8*)(kb + hoff + part * 8) = okb;
    *(u16x8*)(vb + hoff + part * 8) = ovb;
    *(u16x8*)(vtok + toff + part * 8) = ovt;
  }
}

// ---------------------------------------------------------------------------
// per-(bh,chunk): X = (I + strict_tril(kb@kn^T))^-1 ; u=X@vb ; w=X@kb ;
// attn = tril(qn@kn^T). MFMA for all matrix products; wave-specialized phases.
// Outputs packed in MFMA-fragment blob for the scan.
// ---------------------------------------------------------------------------
__global__ __launch_bounds__(256) void k_chunkprep(const u16* __restrict__ qn, const u16* __restrict__ kn,
                                                   const u16* __restrict__ kb, const u16* __restrict__ vb,
                                                   u16* __restrict__ blob) {
  const int blk = blockIdx.x;  // bh*NC + chunk
  const int bh = blk >> 7, ch = blk & 127;
  const int tid = threadIdx.x;
  const int wave = tid >> 6, lane = tid & 63;
  const int g = lane >> 4, li = lane & 15;
  __shared__ u16 kbl[32 * 136], knl[32 * 136], vbl[32 * 136], qnl[32 * 136];
  __shared__ float Af[32][33];   // kb@kn^T (f32)
  __shared__ float Qs[32][33];   // tril(qn@kn^T) (f32)
  __shared__ float Xs[32][33];   // inverse (f32)
  __shared__ float Ts[16][17];   // A21@X11 temp
  __shared__ u16 w_s[32 * 136];  // w row-major bf16

  size_t base = ((size_t)bh * L_ + (size_t)ch * 32) * 128;
#pragma unroll
  for (int rep = 0; rep < 2; ++rep) {
    int lin = rep * 2048 + tid * 8;
    int row = lin >> 7, col = lin & 127;
    *(u16x8*)&kbl[row * 136 + col] = *(const u16x8*)(kb + base + lin);
    *(u16x8*)&knl[row * 136 + col] = *(const u16x8*)(kn + base + lin);
    *(u16x8*)&vbl[row * 136 + col] = *(const u16x8*)(vb + base + lin);
    *(u16x8*)&qnl[row * 136 + col] = *(const u16x8*)(qn + base + lin);
  }
  __syncthreads();

  u16* bp = blob + (size_t)blk * BLOB_ELEMS;

  // ---- phase 1: MFMA products + kt transpose ----
  if (wave < 2) {
    const u16* asrc = (wave == 0) ? kbl : qnl;
    bf16x8 a[2][4], bfr[2][4];
#pragma unroll
    for (int mt = 0; mt < 2; ++mt)
#pragma unroll
      for (int ks = 0; ks < 4; ++ks) {
        a[mt][ks] = *(const bf16x8*)&asrc[(mt * 16 + li) * 136 + ks * 32 + g * 8];
        bfr[mt][ks] = *(const bf16x8*)&knl[(mt * 16 + li) * 136 + ks * 32 + g * 8];
      }
    f32x4 acc[2][2];
#pragma unroll
    for (int mt = 0; mt < 2; ++mt)
#pragma unroll
      for (int nt = 0; nt < 2; ++nt) acc[mt][nt] = (f32x4){0.f, 0.f, 0.f, 0.f};
#pragma unroll
    for (int mt = 0; mt < 2; ++mt)
#pragma unroll
      for (int nt = 0; nt < 2; ++nt)
#pragma unroll
        for (int ks = 0; ks < 4; ++ks)
          acc[mt][nt] = __builtin_amdgcn_mfma_f32_16x16x32_bf16(a[mt][ks], bfr[nt][ks], acc[mt][nt], 0, 0, 0);
    if (wave == 0) {
#pragma unroll
      for (int mt = 0; mt < 2; ++mt)
#pragma unroll
        for (int nt = 0; nt < 2; ++nt)
#pragma unroll
          for (int r = 0; r < 4; ++r)
            Af[mt * 16 + g * 4 + r][nt * 16 + li] = acc[mt][nt][r];
    } else {
#pragma unroll
      for (int mt = 0; mt < 2; ++mt)
#pragma unroll
        for (int nt = 0; nt < 2; ++nt)
#pragma unroll
          for (int r = 0; r < 4; ++r) {
            int row = mt * 16 + g * 4 + r, col = nt * 16 + li;
            Qs[row][col] = (col <= row) ? acc[mt][nt][r] : 0.f;
          }
    }
  } else {
    // kt A-frags: kt[dk][c] = kn[c][dk]; v8 units 0..511 over waves 2,3
#pragma unroll
    for (int it = 0; it < 4; ++it) {
      int v8 = (tid - 128) * 4 + it;
      int f = v8 >> 6, l = v8 & 63;
      int lli = l & 15, lg = l >> 4;
      int dk = f * 16 + lli;
      u16x8 tv;
#pragma unroll
      for (int e = 0; e < 8; ++e) tv[e] = knl[(lg * 8 + e) * 136 + dk];
      *(u16x8*)(bp + KTOFF + (size_t)v8 * 8) = tv;
    }
  }
  __syncthreads();

  // ---- phase 2: solve (wave 0) || AOFF pack (wave 1) ----
  if (wave == 0) {
    if (lane < 32) {
      for (int i = 0; i < 32; ++i) Xs[i][lane] = (i == lane) ? 1.f : 0.f;
      int hb = lane >> 4, j = lane & 15, b0 = hb * 16;
      // column-parallel 16x16 unit-lower-triangular inverse (X11, X22)
      for (int i = j + 1; i < 16; ++i) {
        float s = 0.f;
        for (int m = j; m < i; ++m) s += Af[b0 + i][b0 + m] * Xs[b0 + m][b0 + j];
        Xs[b0 + i][b0 + j] = -s;
      }
    }
    asm volatile("s_waitcnt lgkmcnt(0)" ::: "memory");
    // T = A21 @ X11  (A21 = Af[16:32][0:16])
#pragma unroll
    for (int t = 0; t < 4; ++t) {
      int idx = lane * 4 + t;
      int i = idx >> 4, j = idx & 15;
      float s = 0.f;
      for (int m = 0; m < 16; ++m) s += Af[16 + i][m] * Xs[m][j];
      Ts[i][j] = s;
    }
    asm volatile("s_waitcnt lgkmcnt(0)" ::: "memory");
    // X21 = -X22 @ T
#pragma unroll
    for (int t = 0; t < 4; ++t) {
      int idx = lane * 4 + t;
      int i = idx >> 4, j = idx & 15;
      float s = 0.f;
      for (int m = 0; m < 16; ++m) s += Xs[16 + i][16 + m] * Ts[m][j];
      Xs[16 + i][j] = -s;
    }
  } else if (wave == 1) {
    // AOFF pack: attn A-frags from Qs
#pragma unroll
    for (int mw = 0; mw < 2; ++mw) {
      u16x8 tv;
#pragma unroll
      for (int e = 0; e < 8; ++e) tv[e] = f2bf(Qs[mw * 16 + li][g * 8 + e]);
      *(u16x8*)(bp + AOFF + (size_t)(mw * 64 + lane) * 8) = tv;
    }
  }
  __syncthreads();

  // ---- phase 3: u = X@vb (waves 0,1 -> UTOFF direct) ; w = X@kb (waves 2,3 -> w_s) ----
  {
    bf16x8 xa[2];
#pragma unroll
    for (int mw = 0; mw < 2; ++mw) {
      u16x8 xv;
#pragma unroll
      for (int e = 0; e < 8; ++e) xv[e] = f2bf(Xs[mw * 16 + li][g * 8 + e]);
      xa[mw] = __builtin_bit_cast(bf16x8, xv);
    }
    const u16* bsrc = (wave < 2) ? vbl : kbl;
    const int wsel = wave & 1;
#pragma unroll
    for (int s4 = 0; s4 < 4; ++s4) {
      int sg = wsel * 4 + s4;
      u16x8 bv;
#pragma unroll
      for (int e = 0; e < 8; ++e) bv[e] = bsrc[(g * 8 + e) * 136 + sg * 16 + li];
      bf16x8 bfrag = __builtin_bit_cast(bf16x8, bv);
      f32x4 a0 = (f32x4){0.f, 0.f, 0.f, 0.f};
      f32x4 a1 = (f32x4){0.f, 0.f, 0.f, 0.f};
      a0 = __builtin_amdgcn_mfma_f32_16x16x32_bf16(xa[0], bfrag, a0, 0, 0, 0);
      a1 = __builtin_amdgcn_mfma_f32_16x16x32_bf16(xa[1], bfrag, a1, 0, 0, 0);
      if (wave < 2) {
        u16x4 o0, o1;
#pragma unroll
        for (int r = 0; r < 4; ++r) { o0[r] = f2bf(a0[r]); o1[r] = f2bf(a1[r]); }
        *(u16x4*)(bp + UTOFF + (size_t)((sg * 2 + 0) * 64 + lane) * 4) = o0;
        *(u16x4*)(bp + UTOFF + (size_t)((sg * 2 + 1) * 64 + lane) * 4) = o1;
      } else {
#pragma unroll
        for (int r = 0; r < 4; ++r) {
          w_s[(0 * 16 + g * 4 + r) * 136 + sg * 16 + li] = f2bf(a0[r]);
          w_s[(1 * 16 + g * 4 + r) * 136 + sg * 16 + li] = f2bf(a1[r]);
        }
      }
    }
  }
  __syncthreads();

  // ---- phase 4: WOFF (from w_s) + QOFF (from qnl) A-frag packs ----
#pragma unroll
  for (int it = 0; it < 2; ++it) {
    int v8 = tid * 2 + it;
    int f = v8 >> 6, l = v8 & 63;
    int lli = l & 15, lg = l >> 4;
    int mw = f >> 2, ks = f & 3;
    int row = mw * 16 + lli, c0 = ks * 32 + lg * 8;
    *(u16x8*)(bp + WOFF + (size_t)v8 * 8) = *(const u16x8*)&w_s[row * 136 + c0];
    *(u16x8*)(bp + QOFF + (size_t)v8 * 8) = *(const u16x8*)&qnl[row * 136 + c0];
  }
}

// ---------------------------------------------------------------------------
// sequential inter-chunk scan; 1 wave per block; block = (bh, dv-slice of 16).
// 2-deep register double-buffer (named sets, unrolled x2) hides L2 latency.
// Block swizzle groups all 8 dv-slices of a bh onto one XCD for L2 sharing.
// ---------------------------------------------------------------------------
struct Frags {
  bf16x8 aw[8], aq[8], akt[8], aat[2];
  u16x4 uv[2];
};

DEV void load_frags(Frags& f, const u16* __restrict__ bp, int lane, int sg) {
#pragma unroll
  for (int i = 0; i < 8; ++i)
    f.aw[i] = *(const bf16x8*)&bp[WOFF + ((size_t)(i * 64 + lane)) * 8];
#pragma unroll
  for (int mw = 0; mw < 2; ++mw)
    f.uv[mw] = *(const u16x4*)&bp[UTOFF + ((size_t)((sg * 2 + mw) * 64 + lane)) * 4];
#pragma unroll
  for (int i = 0; i < 8; ++i)
    f.aq[i] = *(const bf16x8*)&bp[QOFF + ((size_t)(i * 64 + lane)) * 8];
#pragma unroll
  for (int mw = 0; mw < 2; ++mw)
    f.aat[mw] = *(const bf16x8*)&bp[AOFF + ((size_t)(mw * 64 + lane)) * 8];
#pragma unroll
  for (int i = 0; i < 8; ++i)
    f.akt[i] = *(const bf16x8*)&bp[KTOFF + ((size_t)(i * 64 + lane)) * 8];
}

DEV void compute_chunk(const Frags& f, f32x4 (&S)[8], u16* st, u16* uft,
                       u16* __restrict__ o_out, size_t obase, int lane) {
  const int g = lane >> 4, li = lane & 15;
  // ---- export S (f32 acc, C-layout) -> bf16 transposed -> B-frags ----
#pragma unroll
  for (int mi = 0; mi < 8; ++mi) {
    u16x4 sv;
#pragma unroll
    for (int r = 0; r < 4; ++r) sv[r] = f2bf(S[mi][r]);
    *(u16x4*)&st[li * 136 + mi * 16 + g * 4] = sv;
  }
  bf16x8 bS[4];
#pragma unroll
  for (int ks = 0; ks < 4; ++ks)
    bS[ks] = *(const bf16x8*)&st[li * 136 + ks * 32 + g * 8];

  // t1 = w_i @ S  (split into two 2-deep chains to halve MFMA latency chain)
  f32x4 t1a[2], t1b[2];
#pragma unroll
  for (int mw = 0; mw < 2; ++mw) {
    t1a[mw] = (f32x4){0.f, 0.f, 0.f, 0.f};
    t1b[mw] = (f32x4){0.f, 0.f, 0.f, 0.f};
    t1a[mw] = __builtin_amdgcn_mfma_f32_16x16x32_bf16(f.aw[mw * 4 + 0], bS[0], t1a[mw], 0, 0, 0);
    t1b[mw] = __builtin_amdgcn_mfma_f32_16x16x32_bf16(f.aw[mw * 4 + 2], bS[2], t1b[mw], 0, 0, 0);
    t1a[mw] = __builtin_amdgcn_mfma_f32_16x16x32_bf16(f.aw[mw * 4 + 1], bS[1], t1a[mw], 0, 0, 0);
    t1b[mw] = __builtin_amdgcn_mfma_f32_16x16x32_bf16(f.aw[mw * 4 + 3], bS[3], t1b[mw], 0, 0, 0);
  }

  // ufix = u_i - t1 -> transposed LDS -> B-frag
#pragma unroll
  for (int mw = 0; mw < 2; ++mw) {
    u16x4 ufv;
#pragma unroll
    for (int r = 0; r < 4; ++r)
      ufv[r] = f2bf(bf2f(f.uv[mw][r]) - (t1a[mw][r] + t1b[mw][r]));
    *(u16x4*)&uft[li * 40 + mw * 16 + g * 4] = ufv;
  }
  bf16x8 bUF = *(const bf16x8*)&uft[li * 40 + g * 8];

  // o = q_i @ S + attn_i @ ufix
  f32x4 oa[2];
  oa[0] = (f32x4){0.f, 0.f, 0.f, 0.f};
  oa[1] = (f32x4){0.f, 0.f, 0.f, 0.f};
#pragma unroll
  for (int mw = 0; mw < 2; ++mw)
#pragma unroll
    for (int ks = 0; ks < 4; ++ks)
      oa[mw] = __builtin_amdgcn_mfma_f32_16x16x32_bf16(f.aq[mw * 4 + ks], bS[ks], oa[mw], 0, 0, 0);
#pragma unroll
  for (int mw = 0; mw < 2; ++mw)
    oa[mw] = __builtin_amdgcn_mfma_f32_16x16x32_bf16(f.aat[mw], bUF, oa[mw], 0, 0, 0);

  // write o (token-major)
#pragma unroll
  for (int mw = 0; mw < 2; ++mw)
#pragma unroll
    for (int r = 0; r < 4; ++r)
      o_out[obase + (size_t)(mw * 16 + r) * 1024] = f2bf(oa[mw][r]);

  // S += k_i^T @ ufix
#pragma unroll
  for (int mi = 0; mi < 8; ++mi)
    S[mi] = __builtin_amdgcn_mfma_f32_16x16x32_bf16(f.akt[mi], bUF, S[mi], 0, 0, 0);
}

__global__ __launch_bounds__(64, 1) void k_scan(const u16* __restrict__ blob, u16* __restrict__ o_out) {
  __shared__ u16 st[16 * 136];   // transposed S (bf16), padded stride 136
  __shared__ u16 uft[16 * 40];   // transposed ufix
  const int bid = blockIdx.x;    // 0..127
  const int bh = (bid & 7) | ((bid >> 6) << 3);
  const int sg = (bid >> 3) & 7;
  const int b = bh >> 3, h = bh & 7;
  const int lane = threadIdx.x;
  const int g = lane >> 4, li = lane & 15;

  f32x4 S[8];
#pragma unroll
  for (int mi = 0; mi < 8; ++mi) S[mi] = (f32x4){0.f, 0.f, 0.f, 0.f};

  const u16* gb = blob + (size_t)bh * NC * BLOB_ELEMS;
  const size_t ob0 = ((size_t)b * L_ + g * 4) * 1024 + h * 128 + sg * 16 + li;

  Frags fa, fb;
  load_frags(fa, gb, lane, sg);
  for (int ch = 0; ch < NC - 2; ch += 2) {
    load_frags(fb, gb + (size_t)(ch + 1) * BLOB_ELEMS, lane, sg);
    compute_chunk(fa, S, st, uft, o_out, ob0 + (size_t)ch * 32 * 1024, lane);
    load_frags(fa, gb + (size_t)(ch + 2) * BLOB_ELEMS, lane, sg);
    compute_chunk(fb, S, st, uft, o_out, ob0 + (size_t)(ch + 1) * 32 * 1024, lane);
  }
  load_frags(fb, gb + (size_t)(NC - 1) * BLOB_ELEMS, lane, sg);
  compute_chunk(fa, S, st, uft, o_out, ob0 + (size_t)(NC - 2) * 32 * 1024, lane);
  compute_chunk(fb, S, st, uft, o_out, ob0 + (size_t)(NC - 1) * 32 * 1024, lane);
}

// ---------------------------------------------------------------------------
// o = g*o + (1-g)*v_token ; RMS over DV ; * o_norm_w ; -> bf16 for final GEMM
// ---------------------------------------------------------------------------
__global__ __launch_bounds__(256) void k_mixnorm(const u16* __restrict__ o_mid, const u16* __restrict__ vtok,
                                                 const float* __restrict__ g, const float* __restrict__ onw,
                                                 u16* __restrict__ omix) {
  int t = blockIdx.x, tid = threadIdx.x;
  int c = tid * 4, h = c >> 7, dk = c & 127;
  float gv = g[t * 8 + h];
  u16x4 ov = *(const u16x4*)(o_mid + (size_t)t * 1024 + c);
  u16x4 vv = *(const u16x4*)(vtok + (size_t)t * 1024 + c);
  float mx[4];
#pragma unroll
  for (int j = 0; j < 4; ++j) mx[j] = gv * bf2f(ov[j]) + (1.f - gv) * bf2f(vv[j]);
  float ss = mx[0] * mx[0] + mx[1] * mx[1] + mx[2] * mx[2] + mx[3] * mx[3];
#pragma unroll
  for (int m = 1; m <= 16; m <<= 1) ss += __shfl_xor(ss, m);
  float r = rsqrtf(ss * (1.f / 128.f) + 1e-5f);
  u16x4 oo;
#pragma unroll
  for (int j = 0; j < 4; ++j) oo[j] = f2bf(mx[j] * r * onw[dk + j]);
  *(u16x4*)(omix + (size_t)t * 1024 + c) = oo;
}

// ---------------------------------------------------------------------------
extern "C" void kernel_launch(void* const* d_in, const int* in_sizes, int n_in,
                              void* d_out, int out_size, void* d_ws, size_t ws_size,
                              hipStream_t stream) {
  const float* hidden = (const float*)d_in[0];
  const float* q_w = (const float*)d_in[1];
  const float* k_w = (const float*)d_in[2];
  const float* v_w = (const float*)d_in[3];
  const float* cqw = (const float*)d_in[4];
  const float* ckw = (const float*)d_in[5];
  const float* cvw = (const float*)d_in[6];
  const float* b_w = (const float*)d_in[7];
  const float* mix_w = (const float*)d_in[8];
  const float* mix_b = (const float*)d_in[9];
  const float* mix_bias = (const float*)d_in[10];
  const float* onw = (const float*)d_in[11];
  const float* o_w = (const float*)d_in[12];

  char* ws = (char*)d_ws;
  size_t off = 0;
  auto alloc = [&](size_t bytes) {
    char* p = ws + off;
    off += (bytes + 255) & ~(size_t)255;
    return p;
  };
  u16* hbf = (u16*)alloc(16777216);      // hidden bf16; reused as omix at the end
  u16* wqkvT = (u16*)alloc((size_t)QKV_N * 1024 * 2);  // [3200][1024]
  u16* woT = (u16*)alloc(2097152);
  float* gg = (float*)alloc(262144);
  u16* qn = (u16*)alloc(16777216);       // reused as scan output o after chunkprep
  u16* kn = (u16*)alloc(16777216);
  u16* kbn = (u16*)alloc(16777216);
  u16* vbn = (u16*)alloc(16777216);
  u16* vtok = (u16*)alloc(16777216);
  u16* blob = (u16*)alloc(71303168);     // 16 bh * 128 ch * 34816 B (fragment blob)
  if (off > ws_size) return;

  // fused qkv GEMM output [8192][3200] aliases the (not-yet-written) blob
  // (safe: conv fully consumes qkv BEFORE chunkprep writes blob)
  u16* qkv = blob;
  u16* obuf = qn;  // scan output aliases qn (dead after chunkprep)

  k_f32_to_bf16<<<8192, 256, 0, stream>>>(hidden, hbf, 2097152);
  k_transpose_w<<<dim3(32, 32, 4), 256, 0, stream>>>(q_w, k_w, v_w, o_w,
                                                     wqkvT, wqkvT + 1024 * 1024,
                                                     wqkvT + 2 * 1024 * 1024, woT);
  k_pack_bg<<<64, 256, 0, stream>>>(b_w, mix_w, wqkvT + (size_t)3072 * 1024);
  gemm_bt<true><<<dim3(25, 64), 256, 0, stream>>>(hbf, wqkvT, qkv, BL, QKV_N, 1024);
  k_conv<<<2048, 256, 0, stream>>>(qkv, cqw, ckw, cvw, mix_b, mix_bias,
                                   qn, kn, kbn, vbn, vtok, gg);
  k_chunkprep<<<2048, 256, 0, stream>>>(qn, kn, kbn, vbn, blob);
  k_scan<<<128, 64, 0, stream>>>(blob, obuf);
  k_mixnorm<<<8192, 256, 0, stream>>>(obuf, vtok, gg, onw, hbf);
  gemm_bt<false><<<dim3(8, 64), 256, 0, stream>>>(hbf, woT, d_out, BL, 1024, 1024);
}